// Round 1
// baseline (234.692 us; speedup 1.0000x reference)
//
#include <hip/hip_runtime.h>
#include <hip/hip_bf16.h>

#define NN 50000
#define NE 800000
#define DIN 300
#define KP1 320
#define DH 96
#define DOUTC 2
#define NG 64

#define NKB 10                        // gemm1 k-blocks (320/32)
#define NFRAG (NKB * 6 * 64)          // 3840 B-fragments of 16 B

#define DSTRIDE 64                    // padded-CSR slots per node
#define NB1 ((NN + 63) / 64)          // 782 gemm1 tiles
#define EPB 1024                      // edges per scatter-role block
#define NB2 ((NN + 31) / 32)          // 1563 agg1g2 blocks (32 nodes each)
#define LROW 104                      // LDS row stride in ushorts (96 + 8 pad)
#define QW 12                         // uint4 (8 bf16) lanes per node row

typedef __attribute__((ext_vector_type(8))) short bf16x8;
typedef __attribute__((ext_vector_type(4))) float f32x4;

__device__ inline unsigned short f2bf(float f) {
    unsigned int u = __float_as_uint(f);
    unsigned int r = (u + 0x7fffu + ((u >> 16) & 1u)) >> 16;
    return (unsigned short)r;
}
__device__ inline float b2f(unsigned short u) {
    return __uint_as_float((unsigned int)u << 16);
}
__device__ inline float blo(unsigned int u) { return __uint_as_float(u << 16); }
__device__ inline float bhi(unsigned int u) { return __uint_as_float(u & 0xffff0000u); }

// ---------------- prep: zero cnt/pooled + both weight transposes ----------------
__global__ void k_prep(int* cnt, float* pooled,
                       const float* __restrict__ W1, unsigned short* __restrict__ wt1f,
                       const float* __restrict__ W2, unsigned short* __restrict__ wt2) {
    int i = blockIdx.x * blockDim.x + threadIdx.x;
    if (i < NN) cnt[i] = 0;
    if (i < NG * DH) pooled[i] = 0.f;
    if (i < NFRAG * 8) {           // W1 -> fragment-major bf16 (gemm1 LDS image)
        int j = i & 7;
        int f = i >> 3;
        int lane = f & 63;
        int ft = f >> 6;           // kb*6 + t
        int t = ft % 6;
        int kb = ft / 6;
        int row = (lane & 15) + 16 * t;
        int col = kb * 32 + (lane >> 4) * 8 + j;
        wt1f[i] = (col < DIN) ? f2bf(W1[(size_t)col * DH + row]) : (unsigned short)0;
    }
    if (i < DH * DH) {             // W2 -> W^T bf16 row-major
        int j = i / DH, k = i - j * DH;
        wt2[i] = f2bf(W2[(size_t)k * DH + j]);
    }
}

// ---------------- GEMM1 / edge-scatter, role-split by blockIdx parity ----------------
__global__ __launch_bounds__(256) void k_g1sc(const float* __restrict__ A,
        const unsigned short* __restrict__ WF, unsigned short* __restrict__ Cb,
        const int* __restrict__ src, const int* __restrict__ dst,
        int* cnt, unsigned short* __restrict__ esrc) {
    __shared__ unsigned short ldsB[NFRAG * 8];   // 61440 B
    const int tid = threadIdx.x;

    if (blockIdx.x & 1) {
        // ---- scatter role: 4 consecutive edges per thread, int4 loads ----
        const int ebase = (blockIdx.x >> 1) * EPB + tid * 4;
        if (ebase + 3 < NE) {
            int4 d4 = *(const int4*)&dst[ebase];
            int4 s4 = *(const int4*)&src[ebase];
            int p0 = atomicAdd(&cnt[d4.x], 1);
            int p1 = atomicAdd(&cnt[d4.y], 1);
            int p2 = atomicAdd(&cnt[d4.z], 1);
            int p3 = atomicAdd(&cnt[d4.w], 1);
            if (p0 < DSTRIDE) esrc[(size_t)d4.x * DSTRIDE + p0] = (unsigned short)s4.x;
            if (p1 < DSTRIDE) esrc[(size_t)d4.y * DSTRIDE + p1] = (unsigned short)s4.y;
            if (p2 < DSTRIDE) esrc[(size_t)d4.z * DSTRIDE + p2] = (unsigned short)s4.z;
            if (p3 < DSTRIDE) esrc[(size_t)d4.w * DSTRIDE + p3] = (unsigned short)s4.w;
        } else {
            for (int e = ebase; e < NE; ++e) {
                int d = dst[e];
                int pos = atomicAdd(&cnt[d], 1);
                if (pos < DSTRIDE) esrc[(size_t)d * DSTRIDE + pos] = (unsigned short)src[e];
            }
        }
        return;
    }

    // ---- gemm role ----
    const int tile = blockIdx.x >> 1;
    {
        const uint4* srcv = (const uint4*)WF;
        uint4* dstv = (uint4*)ldsB;
        #pragma unroll
        for (int f = 0; f < NFRAG / 256; ++f)
            dstv[f * 256 + tid] = srcv[f * 256 + tid];
    }
    __syncthreads();

    const int wv = tid >> 6;
    const int lane = tid & 63;
    const int m = lane & 15;
    const int quad = lane >> 4;
    const int row = tile * 64 + wv * 16 + m;
    const int arow = row < NN ? row : NN - 1;
    const float* ap = A + (size_t)arow * DIN + quad * 8;
    const float4 z4 = make_float4(0.f, 0.f, 0.f, 0.f);
    const bf16x8* lb = (const bf16x8*)ldsB;
    f32x4 acc[6];
    #pragma unroll
    for (int t = 0; t < 6; ++t) acc[t] = (f32x4){0.f, 0.f, 0.f, 0.f};

    float4 pa[4][2];
    #pragma unroll
    for (int i = 0; i < 3; ++i) {
        int kb = i * 32 + quad * 8;
        pa[i][0] = (kb + 4 <= DIN) ? *(const float4*)(ap + i * 32) : z4;
        pa[i][1] = (kb + 8 <= DIN) ? *(const float4*)(ap + i * 32 + 4) : z4;
    }

    #pragma unroll
    for (int i = 0; i < NKB; ++i) {
        if (i + 3 < NKB) {
            int kb = (i + 3) * 32 + quad * 8;
            pa[(i + 3) & 3][0] = (kb + 4 <= DIN) ? *(const float4*)(ap + (i + 3) * 32) : z4;
            pa[(i + 3) & 3][1] = (kb + 8 <= DIN) ? *(const float4*)(ap + (i + 3) * 32 + 4) : z4;
        }
        float4 a0 = pa[i & 3][0], a1 = pa[i & 3][1];
        bf16x8 af;
        af[0] = (short)f2bf(a0.x); af[1] = (short)f2bf(a0.y);
        af[2] = (short)f2bf(a0.z); af[3] = (short)f2bf(a0.w);
        af[4] = (short)f2bf(a1.x); af[5] = (short)f2bf(a1.y);
        af[6] = (short)f2bf(a1.z); af[7] = (short)f2bf(a1.w);
        #pragma unroll
        for (int t = 0; t < 6; ++t) {
            bf16x8 bf = lb[(i * 6 + t) * 64 + lane];
            acc[t] = __builtin_amdgcn_mfma_f32_16x16x32_bf16(af, bf, acc[t], 0, 0, 0);
        }
    }
    const int rbase = tile * 64 + wv * 16 + quad * 4;
    #pragma unroll
    for (int r = 0; r < 4; ++r) {
        int rr = rbase + r;
        if (rr < NN) {
            unsigned short* cp = Cb + (size_t)rr * DH + m;
            #pragma unroll
            for (int t = 0; t < 6; ++t) cp[t * 16] = f2bf(acc[t][r]);
        }
    }
}

// ---------------- agg core: 8-element (uint4) gather lane ----------------
// One thread owns 8 consecutive h-elements of node n (q in [0,12)).
// Per-element edge order and FMA sequence identical to the 24-lane version
// -> bitwise-identical output.
__device__ inline void agg_row8(const uint4* __restrict__ hbq, const int* __restrict__ cnt,
                                const unsigned short* __restrict__ esrc,
                                int n, int q, float dn, int count, float* acc) {
    uint4 u0 = hbq[(size_t)n * QW + q];
    acc[0] = dn * blo(u0.x); acc[1] = dn * bhi(u0.x);
    acc[2] = dn * blo(u0.y); acc[3] = dn * bhi(u0.y);
    acc[4] = dn * blo(u0.z); acc[5] = dn * bhi(u0.z);
    acc[6] = dn * blo(u0.w); acc[7] = dn * bhi(u0.w);
    const int beg = n * DSTRIDE;
    const int end = beg + count;
    int e = beg;
    for (; e + 3 < end; e += 4) {
        int s0 = esrc[e], s1 = esrc[e + 1], s2 = esrc[e + 2], s3 = esrc[e + 3];
        float d0 = rsqrtf(1.0f + (float)cnt[s0]);
        float d1 = rsqrtf(1.0f + (float)cnt[s1]);
        float d2 = rsqrtf(1.0f + (float)cnt[s2]);
        float d3 = rsqrtf(1.0f + (float)cnt[s3]);
        uint4 v0 = hbq[(size_t)s0 * QW + q];
        uint4 v1 = hbq[(size_t)s1 * QW + q];
        uint4 v2 = hbq[(size_t)s2 * QW + q];
        uint4 v3 = hbq[(size_t)s3 * QW + q];
        acc[0] = fmaf(d0, blo(v0.x), acc[0]); acc[1] = fmaf(d0, bhi(v0.x), acc[1]);
        acc[2] = fmaf(d0, blo(v0.y), acc[2]); acc[3] = fmaf(d0, bhi(v0.y), acc[3]);
        acc[4] = fmaf(d0, blo(v0.z), acc[4]); acc[5] = fmaf(d0, bhi(v0.z), acc[5]);
        acc[6] = fmaf(d0, blo(v0.w), acc[6]); acc[7] = fmaf(d0, bhi(v0.w), acc[7]);
        acc[0] = fmaf(d1, blo(v1.x), acc[0]); acc[1] = fmaf(d1, bhi(v1.x), acc[1]);
        acc[2] = fmaf(d1, blo(v1.y), acc[2]); acc[3] = fmaf(d1, bhi(v1.y), acc[3]);
        acc[4] = fmaf(d1, blo(v1.z), acc[4]); acc[5] = fmaf(d1, bhi(v1.z), acc[5]);
        acc[6] = fmaf(d1, blo(v1.w), acc[6]); acc[7] = fmaf(d1, bhi(v1.w), acc[7]);
        acc[0] = fmaf(d2, blo(v2.x), acc[0]); acc[1] = fmaf(d2, bhi(v2.x), acc[1]);
        acc[2] = fmaf(d2, blo(v2.y), acc[2]); acc[3] = fmaf(d2, bhi(v2.y), acc[3]);
        acc[4] = fmaf(d2, blo(v2.z), acc[4]); acc[5] = fmaf(d2, bhi(v2.z), acc[5]);
        acc[6] = fmaf(d2, blo(v2.w), acc[6]); acc[7] = fmaf(d2, bhi(v2.w), acc[7]);
        acc[0] = fmaf(d3, blo(v3.x), acc[0]); acc[1] = fmaf(d3, bhi(v3.x), acc[1]);
        acc[2] = fmaf(d3, blo(v3.y), acc[2]); acc[3] = fmaf(d3, bhi(v3.y), acc[3]);
        acc[4] = fmaf(d3, blo(v3.z), acc[4]); acc[5] = fmaf(d3, bhi(v3.z), acc[5]);
        acc[6] = fmaf(d3, blo(v3.w), acc[6]); acc[7] = fmaf(d3, bhi(v3.w), acc[7]);
    }
    for (; e < end; ++e) {
        int s = esrc[e];
        float ds = rsqrtf(1.0f + (float)cnt[s]);
        uint4 v = hbq[(size_t)s * QW + q];
        acc[0] = fmaf(ds, blo(v.x), acc[0]); acc[1] = fmaf(ds, bhi(v.x), acc[1]);
        acc[2] = fmaf(ds, blo(v.y), acc[2]); acc[3] = fmaf(ds, bhi(v.y), acc[3]);
        acc[4] = fmaf(ds, blo(v.z), acc[4]); acc[5] = fmaf(ds, bhi(v.z), acc[5]);
        acc[6] = fmaf(ds, blo(v.w), acc[6]); acc[7] = fmaf(ds, bhi(v.w), acc[7]);
    }
}

// ---------------- fused agg1 (-> LDS) + gemm2 (LDS A), h2b out ----------------
// 384 threads = 32 nodes x 12 uint4-lanes, one agg item per thread.
__global__ __launch_bounds__(384) void k_agg1g2(const uint4* __restrict__ hbq,
        const int* __restrict__ cnt, const unsigned short* __restrict__ esrc,
        const float* __restrict__ b1, const unsigned short* __restrict__ WT,
        unsigned short* __restrict__ Cb) {
    __shared__ unsigned short a1l[32 * LROW];   // 6656 B
    const int tid = threadIdx.x;
    const int n0 = blockIdx.x * 32;

    // ---- phase A: agg1, one (node, q) per thread ----
    {
        int nl = tid / QW;
        int q = tid - nl * QW;
        int n = n0 + nl;
        uint4 o = make_uint4(0, 0, 0, 0);
        if (n < NN) {
            int count = cnt[n];
            float dn = rsqrtf(1.0f + (float)count);
            if (count > DSTRIDE) count = DSTRIDE;
            float acc[8];
            agg_row8(hbq, cnt, esrc, n, q, dn, count, acc);
            float r[8];
            #pragma unroll
            for (int k = 0; k < 8; ++k)
                r[k] = fmaxf(fmaf(dn, acc[k], b1[q * 8 + k]), 0.f);
            o.x = (unsigned int)f2bf(r[0]) | ((unsigned int)f2bf(r[1]) << 16);
            o.y = (unsigned int)f2bf(r[2]) | ((unsigned int)f2bf(r[3]) << 16);
            o.z = (unsigned int)f2bf(r[4]) | ((unsigned int)f2bf(r[5]) << 16);
            o.w = (unsigned int)f2bf(r[6]) | ((unsigned int)f2bf(r[7]) << 16);
        }
        *(uint4*)&a1l[nl * LROW + q * 8] = o;
    }
    __syncthreads();

    // ---- phase B: gemm2 tile 32x96, A from LDS, first 2 waves only ----
    if (tid < 128) {
        const int wv = tid >> 6;        // 0..1
        const int lane = tid & 63;
        const int m = lane & 15;
        const int quad = lane >> 4;
        const unsigned short* ap = &a1l[(wv * 16 + m) * LROW + quad * 8];
        const unsigned short* wp = WT + (size_t)m * DH + quad * 8;
        bf16x8 af[3];
        #pragma unroll
        for (int i = 0; i < 3; ++i) af[i] = *(const bf16x8*)(ap + i * 32);
        const int rbase = n0 + wv * 16 + quad * 4;
        #pragma unroll 1
        for (int t = 0; t < 6; ++t) {
            f32x4 acc = (f32x4){0.f, 0.f, 0.f, 0.f};
            #pragma unroll
            for (int i = 0; i < 3; ++i) {
                bf16x8 bf = *(const bf16x8*)(wp + (size_t)t * 16 * DH + i * 32);
                acc = __builtin_amdgcn_mfma_f32_16x16x32_bf16(af[i], bf, acc, 0, 0, 0);
            }
            #pragma unroll
            for (int r = 0; r < 4; ++r) {
                int rr = rbase + r;
                if (rr < NN) Cb[(size_t)rr * DH + m + t * 16] = f2bf(acc[r]);
            }
        }
    }
}

// ---------------- agg2 fused with mean-pool partial accumulation ----------------
// Same agg math as before (bitwise-identical per-node result), but instead of
// materializing a 19.2 MB fp32 hbuf and re-reading it in a pool kernel, each
// block accumulates its nodes' relu outputs into a small LDS pool (batch is
// sorted, so a 22-node block spans ~1 graph; 4 slots + global-atomic fallback
// covers any split) and flushes once per (graph,feature).
__global__ __launch_bounds__(256) void k_agg2pool(const uint4* __restrict__ hbq,
        const int* __restrict__ cnt, const unsigned short* __restrict__ esrc,
        const float* __restrict__ b2, const int* __restrict__ batch,
        float* __restrict__ pooled) {
    __shared__ float lpool[4 * DH];
    __shared__ int g0s;
    const int tid = threadIdx.x;
    for (int i = tid; i < 4 * DH; i += 256) lpool[i] = 0.f;
    if (tid == 0) {
        int nfirst = (blockIdx.x * 256) / QW;
        g0s = batch[nfirst < NN ? nfirst : NN - 1];
    }
    __syncthreads();
    const int g0 = g0s;
    const int gid = blockIdx.x * 256 + tid;
    if (gid < NN * QW) {
        int n = gid / QW;
        int q = gid - n * QW;
        int count = cnt[n];
        float dn = rsqrtf(1.0f + (float)count);
        if (count > DSTRIDE) count = DSTRIDE;
        float acc[8];
        agg_row8(hbq, cnt, esrc, n, q, dn, count, acc);
        float r[8];
        #pragma unroll
        for (int k = 0; k < 8; ++k)
            r[k] = fmaxf(fmaf(dn, acc[k], b2[q * 8 + k]), 0.f);
        int g = batch[n];
        int slot = g - g0;
        if (slot < 4) {
            float* lp = &lpool[slot * DH + q * 8];
            #pragma unroll
            for (int k = 0; k < 8; ++k) atomicAdd(&lp[k], r[k]);
        } else {   // pathological graph split (graph with <22 nodes); safe fallback
            float* gp = &pooled[(size_t)g * DH + q * 8];
            #pragma unroll
            for (int k = 0; k < 8; ++k) atomicAdd(&gp[k], r[k]);
        }
    }
    __syncthreads();
    for (int i = tid; i < 4 * DH; i += 256) {
        float v = lpool[i];
        if (v != 0.f) {
            int slot = i / DH, f = i - slot * DH;
            atomicAdd(&pooled[(size_t)(g0 + slot) * DH + f], v);
        }
    }
}

// ---------------- FC: per-graph counts via binary search on sorted batch ----------------
__global__ void k_fc(const float* __restrict__ pooled, const int* __restrict__ batch,
                     const float* __restrict__ Wfc, const float* __restrict__ bfc,
                     float* __restrict__ out) {
    const int t = threadIdx.x;
    if (t >= NG * DOUTC) return;
    const int g = t / DOUTC;
    const int c = t - g * DOUTC;
    int lo = 0, hi = NN;
    while (lo < hi) { int mid = (lo + hi) >> 1; if (batch[mid] < g) lo = mid + 1; else hi = mid; }
    const int s = lo;
    hi = NN;
    while (lo < hi) { int mid = (lo + hi) >> 1; if (batch[mid] < g + 1) lo = mid + 1; else hi = mid; }
    float inv = 1.f / fmaxf((float)(lo - s), 1.f);
    float acc = bfc[c];
    #pragma unroll 8
    for (int j = 0; j < DH; ++j)
        acc += pooled[g * DH + j] * inv * Wfc[j * DOUTC + c];
    out[g * DOUTC + c] = acc;
}

extern "C" void kernel_launch(void* const* d_in, const int* in_sizes, int n_in,
                              void* d_out, int out_size, void* d_ws, size_t ws_size,
                              hipStream_t stream) {
    const float* x   = (const float*)d_in[0];
    const float* W1  = (const float*)d_in[1];
    const float* b1  = (const float*)d_in[2];
    const float* W2  = (const float*)d_in[3];
    const float* b2  = (const float*)d_in[4];
    const float* Wfc = (const float*)d_in[5];
    const float* bfc = (const float*)d_in[6];
    const int* src   = (const int*)d_in[7];
    const int* dst   = (const int*)d_in[8];
    const int* batch = (const int*)d_in[9];
    float* out = (float*)d_out;

    unsigned short* hb  = (unsigned short*)d_ws;        // NN*DH bf16 (gemm1 out)
    unsigned short* h2b = hb + (size_t)NN * DH;         // NN*DH bf16 (gemm2 out, distinct)
    float* hbuf  = (float*)(h2b + (size_t)NN * DH);     // NN*DH f32 (slot kept, unused)
    float* pooled= hbuf + (size_t)NN * DH;              // NG*DH
    int* cnt     = (int*)(pooled + NG * DH);            // NN
    unsigned short* esrc = (unsigned short*)(cnt + NN);    // NN*DSTRIDE ushort
    unsigned short* wt1f = esrc + (size_t)NN * DSTRIDE;    // NFRAG*8
    unsigned short* wt2  = wt1f + NFRAG * 8;               // DH*DH
    (void)hbuf;

    const int TB = 256;
    k_prep<<<(NN + TB - 1) / TB, TB, 0, stream>>>(cnt, pooled, W1, wt1f, W2, wt2);
    // layer 1 GEMM and padded-CSR scatter, role-split across one grid
    k_g1sc<<<NB1 * 2, 256, 0, stream>>>(x, wt1f, hb, src, dst, cnt, esrc);
    // fused agg1 (-> LDS) + gemm2 (-> h2b)
    k_agg1g2<<<NB2, 384, 0, stream>>>((const uint4*)hb, cnt, esrc, b1, wt2, h2b);
    // agg2 gathers h2b, accumulates pooled sums directly (pool kernel fused away)
    k_agg2pool<<<(NN * QW + TB - 1) / TB, TB, 0, stream>>>(
        (const uint4*)h2b, cnt, esrc, b2, batch, pooled);
    // fc
    k_fc<<<1, 128, 0, stream>>>(pooled, batch, Wfc, bfc, out);
}